// Round 12
// baseline (205.493 us; speedup 1.0000x reference)
//
#include <hip/hip_runtime.h>

#define HID 128
#define LN_EPS 1e-5f
#define LDSW 136  // LDS row stride in shorts (272 B): b128 reads at worst 2-way aliasing (free, m136)

typedef __attribute__((ext_vector_type(8))) short bf16x8;
typedef __attribute__((ext_vector_type(4))) float f32x4;

static __device__ __forceinline__ unsigned short f2bf(float f) {
  unsigned int x = __float_as_uint(f);
  x += 0x7fffu + ((x >> 16) & 1u);  // RNE
  return (unsigned short)(x >> 16);
}
static __device__ __forceinline__ float bflo(unsigned int u) { return __uint_as_float(u << 16); }
static __device__ __forceinline__ float bfhi(unsigned int u) { return __uint_as_float(u & 0xffff0000u); }

// ---- fused: bf16 converts (BW-bound blocks) + rank pass (atomic-bound blocks) ----
__global__ __launch_bounds__(256) void k_cvt_rank(const float* __restrict__ h,
                                                  const float* __restrict__ w1,
                                                  const float* __restrict__ w2,
                                                  uint2* __restrict__ hb,
                                                  uint2* __restrict__ w1b,
                                                  uint2* __restrict__ w2b,
                                                  int nh4, int nw4,
                                                  const int* __restrict__ ei,
                                                  int* __restrict__ counts,
                                                  int* __restrict__ rank,
                                                  int nE, int EB) {
  if ((int)blockIdx.x < EB) {
    const int e = blockIdx.x * 256 + threadIdx.x;
    if (e < nE) {
      const int d = ei[nE + e];
      rank[e] = atomicAdd(&counts[d], 1);  // one atomic pass: counts AND slot ranks
    }
    return;
  }
  const int total = nh4 + 2 * nw4;
  const int stride = (gridDim.x - EB) * 256;
  for (int i = (blockIdx.x - EB) * 256 + threadIdx.x; i < total; i += stride) {
    const float* src;
    uint2* dst;
    int off;
    if (i < nh4) { src = h; dst = hb; off = i; }
    else if (i < nh4 + nw4) { src = w1; dst = w1b; off = i - nh4; }
    else { src = w2; dst = w2b; off = i - nh4 - nw4; }
    const float4 v = reinterpret_cast<const float4*>(src)[off];
    uint2 p;
    p.x = (unsigned)f2bf(v.x) | ((unsigned)f2bf(v.y) << 16);
    p.y = (unsigned)f2bf(v.z) | ((unsigned)f2bf(v.w) << 16);
    dst[off] = p;
  }
}

// ---- single-pass scan, decoupled lookback (196 blocks, all co-resident) ----
__global__ __launch_bounds__(256) void k_scanLB(const int* __restrict__ counts,
                                                int* __restrict__ offsets,
                                                unsigned long long* st, int n, int nb) {
  __shared__ int sm[256];
  __shared__ int baseSh;
  const int t = threadIdx.x;
  const int bid = blockIdx.x;
  const int i = bid * 256 + t;
  const int v = (i < n) ? counts[i] : 0;
  int incl = v;
  sm[t] = incl;
  __syncthreads();
#pragma unroll
  for (int off = 1; off < 256; off <<= 1) {
    const int other = (t >= off) ? sm[t - off] : 0;
    __syncthreads();
    incl += other;
    sm[t] = incl;
    __syncthreads();
  }
  const int total = sm[255];

  if (bid == 0) {
    if (t == 0) {
      atomicExch(&st[0], (2ULL << 32) | (unsigned)total);
      baseSh = 0;
    }
  } else {
    if (t == 255)
      atomicExch(&st[bid], (1ULL << 32) | (unsigned)total);
    if (t == 0) {
      long long base = 0;
      int j = bid - 1;
      while (j >= 0) {
        unsigned long long p;
        while (((p = atomicAdd(&st[j], 0ULL)) >> 32) == 0) __builtin_amdgcn_s_sleep(1);
        base += (unsigned)p;
        if ((p >> 32) == 2ULL) break;
        --j;
      }
      atomicExch(&st[bid], (2ULL << 32) | (unsigned)(base + total));
      baseSh = (int)base;
    }
  }
  __syncthreads();
  const int base = baseSh;
  if (i < n) offsets[i] = base + incl - v;
  if (bid == nb - 1 && t == 255) offsets[n] = base + total;
}

// ---- atomic-free scatter: esrc[offsets[d] + rank[e]] = src ----
__global__ __launch_bounds__(256) void k_scat(const int* __restrict__ ei,
                                              const int* __restrict__ rank,
                                              const int* __restrict__ offsets,
                                              int* __restrict__ esrc, int nE) {
  const int e = blockIdx.x * 256 + threadIdx.x;
  if (e >= nE) return;
  const int d = ei[nE + e];
  esrc[offsets[d] + rank[e]] = ei[e];
}

// ---- gather (16 lanes/node, uint4 loads, 4-deep MLP) ----
__global__ __launch_bounds__(256) void k_gather(const unsigned short* __restrict__ hbf,
                                                const int* __restrict__ offsets,
                                                const int* __restrict__ esrc,
                                                const float* __restrict__ eps,
                                                unsigned short* __restrict__ zbf, int nNodes) {
  const int gid = blockIdx.x * 256 + threadIdx.x;
  const int node = gid >> 4;
  if (node >= nNodes) return;
  const int col8 = (threadIdx.x & 15) * 8;
  const float c = 1.0f + eps[0];

  const uint4 hv = *reinterpret_cast<const uint4*>(hbf + (size_t)node * HID + col8);
  float a0 = c * bflo(hv.x), a1 = c * bfhi(hv.x);
  float a2 = c * bflo(hv.y), a3 = c * bfhi(hv.y);
  float a4 = c * bflo(hv.z), a5 = c * bfhi(hv.z);
  float a6 = c * bflo(hv.w), a7 = c * bfhi(hv.w);

  const int beg = offsets[node], end = offsets[node + 1];
  int e = beg;
  for (; e + 3 < end; e += 4) {  // 4 independent 16B row-slices in flight
    const int s0 = esrc[e], s1 = esrc[e + 1], s2 = esrc[e + 2], s3 = esrc[e + 3];
    const uint4 v0 = *reinterpret_cast<const uint4*>(hbf + (size_t)s0 * HID + col8);
    const uint4 v1 = *reinterpret_cast<const uint4*>(hbf + (size_t)s1 * HID + col8);
    const uint4 v2 = *reinterpret_cast<const uint4*>(hbf + (size_t)s2 * HID + col8);
    const uint4 v3 = *reinterpret_cast<const uint4*>(hbf + (size_t)s3 * HID + col8);
    a0 += (bflo(v0.x) + bflo(v1.x)) + (bflo(v2.x) + bflo(v3.x));
    a1 += (bfhi(v0.x) + bfhi(v1.x)) + (bfhi(v2.x) + bfhi(v3.x));
    a2 += (bflo(v0.y) + bflo(v1.y)) + (bflo(v2.y) + bflo(v3.y));
    a3 += (bfhi(v0.y) + bfhi(v1.y)) + (bfhi(v2.y) + bfhi(v3.y));
    a4 += (bflo(v0.z) + bflo(v1.z)) + (bflo(v2.z) + bflo(v3.z));
    a5 += (bfhi(v0.z) + bfhi(v1.z)) + (bfhi(v2.z) + bfhi(v3.z));
    a6 += (bflo(v0.w) + bflo(v1.w)) + (bflo(v2.w) + bflo(v3.w));
    a7 += (bfhi(v0.w) + bfhi(v1.w)) + (bfhi(v2.w) + bfhi(v3.w));
  }
  for (; e < end; ++e) {
    const uint4 v0 = *reinterpret_cast<const uint4*>(hbf + (size_t)esrc[e] * HID + col8);
    a0 += bflo(v0.x); a1 += bfhi(v0.x); a2 += bflo(v0.y); a3 += bfhi(v0.y);
    a4 += bflo(v0.z); a5 += bfhi(v0.z); a6 += bflo(v0.w); a7 += bfhi(v0.w);
  }
  uint4 o;
  o.x = (unsigned)f2bf(a0) | ((unsigned)f2bf(a1) << 16);
  o.y = (unsigned)f2bf(a2) | ((unsigned)f2bf(a3) << 16);
  o.z = (unsigned)f2bf(a4) | ((unsigned)f2bf(a5) << 16);
  o.w = (unsigned)f2bf(a6) | ((unsigned)f2bf(a7) << 16);
  *reinterpret_cast<uint4*>(zbf + (size_t)node * HID + col8) = o;
}

// ---- fused MFMA, column-split; residual from bf16 hbf; params prefetched ----
__global__ __launch_bounds__(256) void k_mmf(const unsigned short* __restrict__ zbf,
                                             const unsigned short* __restrict__ w1,
                                             const unsigned short* __restrict__ w2,
                                             const float* __restrict__ b1,
                                             const float* __restrict__ b2,
                                             const unsigned short* __restrict__ hbf,
                                             const float* __restrict__ gamma,
                                             const float* __restrict__ beta,
                                             float* __restrict__ out) {
  __shared__ unsigned short yt[16][LDSW];
  __shared__ float lnp[16][4][2];
  const int wave = threadIdx.x >> 6;
  const int l = threadIdx.x & 63;
  const int row0 = blockIdx.x * 16;
  const int lr = l & 15;
  const int lq = l >> 4;

  // prefetch: bf16 h residual + epilogue params; latency hides under MFMAs
  float hres[2][4];
#pragma unroll
  for (int j = 0; j < 2; ++j) {
    const int cc = (wave * 2 + j) * 16 + lr;
#pragma unroll
    for (int r = 0; r < 4; ++r) {
      const unsigned short u = hbf[(size_t)(row0 + lq * 4 + r) * HID + cc];
      hres[j][r] = __uint_as_float((unsigned)u << 16);
    }
  }
  float bs1[2], bs2[2], gg[2], bb[2];
#pragma unroll
  for (int j = 0; j < 2; ++j) {
    const int cc = (wave * 2 + j) * 16 + lr;
    bs1[j] = b1[cc]; bs2[j] = b2[cc]; gg[j] = gamma[cc]; bb[j] = beta[cc];
  }

  bf16x8 a[4];
#pragma unroll
  for (int ks = 0; ks < 4; ++ks)
    a[ks] = *reinterpret_cast<const bf16x8*>(zbf + (size_t)(row0 + lr) * HID + ks * 32 + lq * 8);

  f32x4 acc[2];
#pragma unroll
  for (int j = 0; j < 2; ++j) acc[j] = (f32x4){0.f, 0.f, 0.f, 0.f};
#pragma unroll
  for (int j = 0; j < 2; ++j) {
    const unsigned short* wb = w1 + (size_t)((wave * 2 + j) * 16 + lr) * HID + lq * 8;
#pragma unroll
    for (int ks = 0; ks < 4; ++ks) {
      const bf16x8 b = *reinterpret_cast<const bf16x8*>(wb + ks * 32);
      acc[j] = __builtin_amdgcn_mfma_f32_16x16x32_bf16(a[ks], b, acc[j], 0, 0, 0);
    }
  }

#pragma unroll
  for (int j = 0; j < 2; ++j) {
    const int cc = (wave * 2 + j) * 16 + lr;
#pragma unroll
    for (int r = 0; r < 4; ++r)
      yt[lq * 4 + r][cc] = f2bf(fmaxf(acc[j][r] + bs1[j], 0.f));
  }
  __syncthreads();

  bf16x8 a2[4];
#pragma unroll
  for (int ks = 0; ks < 4; ++ks)
    a2[ks] = *reinterpret_cast<const bf16x8*>(&yt[lr][ks * 32 + lq * 8]);

#pragma unroll
  for (int j = 0; j < 2; ++j) acc[j] = (f32x4){0.f, 0.f, 0.f, 0.f};
#pragma unroll
  for (int j = 0; j < 2; ++j) {
    const unsigned short* wb = w2 + (size_t)((wave * 2 + j) * 16 + lr) * HID + lq * 8;
#pragma unroll
    for (int ks = 0; ks < 4; ++ks) {
      const bf16x8 b = *reinterpret_cast<const bf16x8*>(wb + ks * 32);
      acc[j] = __builtin_amdgcn_mfma_f32_16x16x32_bf16(a2[ks], b, acc[j], 0, 0, 0);
    }
  }

#pragma unroll
  for (int j = 0; j < 2; ++j)
#pragma unroll
    for (int r = 0; r < 4; ++r)
      acc[j][r] += bs2[j] + hres[j][r];

#pragma unroll
  for (int r = 0; r < 4; ++r) {
    float s = acc[0][r] + acc[1][r];
    float ss = acc[0][r] * acc[0][r] + acc[1][r] * acc[1][r];
#pragma unroll
    for (int m = 1; m < 16; m <<= 1) {
      s += __shfl_xor(s, m, 64);
      ss += __shfl_xor(ss, m, 64);
    }
    if (lr == 0) {
      lnp[lq * 4 + r][wave][0] = s;
      lnp[lq * 4 + r][wave][1] = ss;
    }
  }
  __syncthreads();

  float mu_[4], rstd_[4];
#pragma unroll
  for (int r = 0; r < 4; ++r) {
    const int rt = lq * 4 + r;
    float s = 0.f, ss = 0.f;
#pragma unroll
    for (int w = 0; w < 4; ++w) {
      const float2 p = *reinterpret_cast<const float2*>(&lnp[rt][w][0]);
      s += p.x;
      ss += p.y;
    }
    const float mu = s * (1.f / 128.f);
    const float var = ss * (1.f / 128.f) - mu * mu;
    mu_[r] = mu;
    rstd_[r] = rsqrtf(var + LN_EPS);
  }
#pragma unroll
  for (int j = 0; j < 2; ++j) {
    const int cc = (wave * 2 + j) * 16 + lr;
#pragma unroll
    for (int r = 0; r < 4; ++r) {
      const int row = row0 + lq * 4 + r;
      const float o = (acc[j][r] - mu_[r]) * rstd_[r] * gg[j] + bb[j];
      out[(size_t)row * HID + cc] = fmaxf(o, 0.f);
    }
  }
}

extern "C" void kernel_launch(void* const* d_in, const int* in_sizes, int n_in,
                              void* d_out, int out_size, void* d_ws, size_t ws_size,
                              hipStream_t stream) {
  const float* h     = (const float*)d_in[0];
  const int*   ei    = (const int*)d_in[1];
  const float* W1    = (const float*)d_in[2];
  const float* b1    = (const float*)d_in[3];
  const float* W2    = (const float*)d_in[4];
  const float* b2    = (const float*)d_in[5];
  const float* eps   = (const float*)d_in[6];
  const float* gamma = (const float*)d_in[7];
  const float* beta  = (const float*)d_in[8];

  const int nNodes = in_sizes[0] / HID;     // 50000
  const int nE     = in_sizes[1] / 2;       // 640000
  const int nb     = (nNodes + 255) / 256;  // 196
  const int nh4    = nNodes * HID / 4;      // 1.6M
  const int nw4    = HID * HID / 4;         // 4096

  // ws layout (ints; bf16 regions 16B-aligned):
  int* counts  = (int*)d_ws;
  int* offsets = counts + nNodes;                       // @ 50000
  unsigned long long* st = (unsigned long long*)(counts + 100002);
  int* rank    = counts + 100800;                       // byte 403200, 16B-aligned
  int* esrc    = rank + nE;                             // @ 740800
  unsigned short* hbf  = (unsigned short*)(esrc + nE);  // byte 5,523,200
  unsigned short* zbf  = hbf + (size_t)nNodes * HID;    // +12.8 MB
  unsigned short* w1bf = zbf + (size_t)nNodes * HID;    // +12.8 MB
  unsigned short* w2bf = w1bf + HID * HID;              // +32 KB (total ~31.2 MB)

  // one memset zeroes counts AND lookback state (offsets in between: harmless)
  hipMemsetAsync(counts, 0, (size_t)(100002 + 2 * nb) * sizeof(int), stream);

  const int EB = (nE + 255) / 256;          // 2500 edge blocks
  k_cvt_rank<<<EB + 2048, 256, 0, stream>>>(h, W1, W2, (uint2*)hbf, (uint2*)w1bf, (uint2*)w2bf,
                                            nh4, nw4, ei, counts, rank, nE, EB);
  k_scanLB<<<nb, 256, 0, stream>>>(counts, offsets, st, nNodes, nb);
  k_scat<<<EB, 256, 0, stream>>>(ei, rank, offsets, esrc, nE);

  k_gather<<<(nNodes * 16 + 255) / 256, 256, 0, stream>>>(hbf, offsets, esrc, eps, zbf, nNodes);

  const int nTiles = nNodes / 16;            // 3125
  k_mmf<<<nTiles, 256, 0, stream>>>(zbf, w1bf, w2bf, b1, b2, hbf, gamma, beta,
                                    (float*)d_out);
}

// Round 13
// 201.603 us; speedup vs baseline: 1.0193x; 1.0193x over previous
//
#include <hip/hip_runtime.h>

#define HID 128
#define LN_EPS 1e-5f
#define LDSW 136   // LDS row stride in shorts (272 B): b128 reads at worst 2-way aliasing (free, m136)
#define CPAD 32    // counters padded to 1 per 128 B line (32 ints)

typedef __attribute__((ext_vector_type(8))) short bf16x8;
typedef __attribute__((ext_vector_type(4))) float f32x4;

static __device__ __forceinline__ unsigned short f2bf(float f) {
  unsigned int x = __float_as_uint(f);
  x += 0x7fffu + ((x >> 16) & 1u);  // RNE
  return (unsigned short)(x >> 16);
}
static __device__ __forceinline__ float bflo(unsigned int u) { return __uint_as_float(u << 16); }
static __device__ __forceinline__ float bfhi(unsigned int u) { return __uint_as_float(u & 0xffff0000u); }

// ---- fused: bf16 converts (BW-bound blocks) + rank pass (atomic-bound blocks) ----
// counts padded: counter for dst d lives at counts[d*CPAD] (own 128B line).
__global__ __launch_bounds__(256) void k_cvt_rank(const float* __restrict__ h,
                                                  const float* __restrict__ w1,
                                                  const float* __restrict__ w2,
                                                  uint2* __restrict__ hb,
                                                  uint2* __restrict__ w1b,
                                                  uint2* __restrict__ w2b,
                                                  int nh4, int nw4,
                                                  const int* __restrict__ ei,
                                                  int* __restrict__ counts,
                                                  int* __restrict__ rank,
                                                  int nE, int EB) {
  if ((int)blockIdx.x < EB) {
    const int e = blockIdx.x * 256 + threadIdx.x;
    if (e < nE) {
      const int d = ei[nE + e];
      rank[e] = atomicAdd(&counts[(size_t)d * CPAD], 1);
    }
    return;
  }
  const int total = nh4 + 2 * nw4;
  const int stride = (gridDim.x - EB) * 256;
  for (int i = (blockIdx.x - EB) * 256 + threadIdx.x; i < total; i += stride) {
    const float* src;
    uint2* dst;
    int off;
    if (i < nh4) { src = h; dst = hb; off = i; }
    else if (i < nh4 + nw4) { src = w1; dst = w1b; off = i - nh4; }
    else { src = w2; dst = w2b; off = i - nh4 - nw4; }
    const float4 v = reinterpret_cast<const float4*>(src)[off];
    uint2 p;
    p.x = (unsigned)f2bf(v.x) | ((unsigned)f2bf(v.y) << 16);
    p.y = (unsigned)f2bf(v.z) | ((unsigned)f2bf(v.w) << 16);
    dst[off] = p;
  }
}

// ---- single-pass scan (decoupled lookback; 196 blocks, all co-resident) ----
// reads padded counters at stride CPAD.
__global__ __launch_bounds__(256) void k_scanLB(const int* __restrict__ counts,
                                                int* __restrict__ offsets,
                                                unsigned long long* st, int n, int nb) {
  __shared__ int sm[256];
  __shared__ int baseSh;
  const int t = threadIdx.x;
  const int bid = blockIdx.x;
  const int i = bid * 256 + t;
  const int v = (i < n) ? counts[(size_t)i * CPAD] : 0;
  int incl = v;
  sm[t] = incl;
  __syncthreads();
#pragma unroll
  for (int off = 1; off < 256; off <<= 1) {
    const int other = (t >= off) ? sm[t - off] : 0;
    __syncthreads();
    incl += other;
    sm[t] = incl;
    __syncthreads();
  }
  const int total = sm[255];

  if (bid == 0) {
    if (t == 0) {
      atomicExch(&st[0], (2ULL << 32) | (unsigned)total);
      baseSh = 0;
    }
  } else {
    if (t == 255)
      atomicExch(&st[bid], (1ULL << 32) | (unsigned)total);
    if (t == 0) {
      long long base = 0;
      int j = bid - 1;
      while (j >= 0) {
        unsigned long long p;
        while (((p = atomicAdd(&st[j], 0ULL)) >> 32) == 0) __builtin_amdgcn_s_sleep(1);
        base += (unsigned)p;
        if ((p >> 32) == 2ULL) break;
        --j;
      }
      atomicExch(&st[bid], (2ULL << 32) | (unsigned)(base + total));
      baseSh = (int)base;
    }
  }
  __syncthreads();
  const int base = baseSh;
  if (i < n) offsets[i] = base + incl - v;
  if (bid == nb - 1 && t == 255) offsets[n] = base + total;
}

// ---- atomic-free scatter: esrc[offsets[d] + rank[e]] = src ----
__global__ __launch_bounds__(256) void k_scat(const int* __restrict__ ei,
                                              const int* __restrict__ rank,
                                              const int* __restrict__ offsets,
                                              int* __restrict__ esrc, int nE) {
  const int e = blockIdx.x * 256 + threadIdx.x;
  if (e >= nE) return;
  const int d = ei[nE + e];
  esrc[offsets[d] + rank[e]] = ei[e];
}

// ---- gather (16 lanes/node, uint4 loads, 4-deep MLP) ----
__global__ __launch_bounds__(256) void k_gather(const unsigned short* __restrict__ hbf,
                                                const int* __restrict__ offsets,
                                                const int* __restrict__ esrc,
                                                const float* __restrict__ eps,
                                                unsigned short* __restrict__ zbf, int nNodes) {
  const int gid = blockIdx.x * 256 + threadIdx.x;
  const int node = gid >> 4;
  if (node >= nNodes) return;
  const int col8 = (threadIdx.x & 15) * 8;
  const float c = 1.0f + eps[0];

  const uint4 hv = *reinterpret_cast<const uint4*>(hbf + (size_t)node * HID + col8);
  float a0 = c * bflo(hv.x), a1 = c * bfhi(hv.x);
  float a2 = c * bflo(hv.y), a3 = c * bfhi(hv.y);
  float a4 = c * bflo(hv.z), a5 = c * bfhi(hv.z);
  float a6 = c * bflo(hv.w), a7 = c * bfhi(hv.w);

  const int beg = offsets[node], end = offsets[node + 1];
  int e = beg;
  for (; e + 3 < end; e += 4) {
    const int s0 = esrc[e], s1 = esrc[e + 1], s2 = esrc[e + 2], s3 = esrc[e + 3];
    const uint4 v0 = *reinterpret_cast<const uint4*>(hbf + (size_t)s0 * HID + col8);
    const uint4 v1 = *reinterpret_cast<const uint4*>(hbf + (size_t)s1 * HID + col8);
    const uint4 v2 = *reinterpret_cast<const uint4*>(hbf + (size_t)s2 * HID + col8);
    const uint4 v3 = *reinterpret_cast<const uint4*>(hbf + (size_t)s3 * HID + col8);
    a0 += (bflo(v0.x) + bflo(v1.x)) + (bflo(v2.x) + bflo(v3.x));
    a1 += (bfhi(v0.x) + bfhi(v1.x)) + (bfhi(v2.x) + bfhi(v3.x));
    a2 += (bflo(v0.y) + bflo(v1.y)) + (bflo(v2.y) + bflo(v3.y));
    a3 += (bfhi(v0.y) + bfhi(v1.y)) + (bfhi(v2.y) + bfhi(v3.y));
    a4 += (bflo(v0.z) + bflo(v1.z)) + (bflo(v2.z) + bflo(v3.z));
    a5 += (bfhi(v0.z) + bfhi(v1.z)) + (bfhi(v2.z) + bfhi(v3.z));
    a6 += (bflo(v0.w) + bflo(v1.w)) + (bflo(v2.w) + bflo(v3.w));
    a7 += (bfhi(v0.w) + bfhi(v1.w)) + (bfhi(v2.w) + bfhi(v3.w));
  }
  for (; e < end; ++e) {
    const uint4 v0 = *reinterpret_cast<const uint4*>(hbf + (size_t)esrc[e] * HID + col8);
    a0 += bflo(v0.x); a1 += bfhi(v0.x); a2 += bflo(v0.y); a3 += bfhi(v0.y);
    a4 += bflo(v0.z); a5 += bfhi(v0.z); a6 += bflo(v0.w); a7 += bfhi(v0.w);
  }
  uint4 o;
  o.x = (unsigned)f2bf(a0) | ((unsigned)f2bf(a1) << 16);
  o.y = (unsigned)f2bf(a2) | ((unsigned)f2bf(a3) << 16);
  o.z = (unsigned)f2bf(a4) | ((unsigned)f2bf(a5) << 16);
  o.w = (unsigned)f2bf(a6) | ((unsigned)f2bf(a7) << 16);
  *reinterpret_cast<uint4*>(zbf + (size_t)node * HID + col8) = o;
}

// ---- fused MFMA, column-split; residual from bf16 hbf; params prefetched ----
__global__ __launch_bounds__(256) void k_mmf(const unsigned short* __restrict__ zbf,
                                             const unsigned short* __restrict__ w1,
                                             const unsigned short* __restrict__ w2,
                                             const float* __restrict__ b1,
                                             const float* __restrict__ b2,
                                             const unsigned short* __restrict__ hbf,
                                             const float* __restrict__ gamma,
                                             const float* __restrict__ beta,
                                             float* __restrict__ out) {
  __shared__ unsigned short yt[16][LDSW];
  __shared__ float lnp[16][4][2];
  const int wave = threadIdx.x >> 6;
  const int l = threadIdx.x & 63;
  const int row0 = blockIdx.x * 16;
  const int lr = l & 15;
  const int lq = l >> 4;

  float hres[2][4];
#pragma unroll
  for (int j = 0; j < 2; ++j) {
    const int cc = (wave * 2 + j) * 16 + lr;
#pragma unroll
    for (int r = 0; r < 4; ++r) {
      const unsigned short u = hbf[(size_t)(row0 + lq * 4 + r) * HID + cc];
      hres[j][r] = __uint_as_float((unsigned)u << 16);
    }
  }
  float bs1[2], bs2[2], gg[2], bb[2];
#pragma unroll
  for (int j = 0; j < 2; ++j) {
    const int cc = (wave * 2 + j) * 16 + lr;
    bs1[j] = b1[cc]; bs2[j] = b2[cc]; gg[j] = gamma[cc]; bb[j] = beta[cc];
  }

  bf16x8 a[4];
#pragma unroll
  for (int ks = 0; ks < 4; ++ks)
    a[ks] = *reinterpret_cast<const bf16x8*>(zbf + (size_t)(row0 + lr) * HID + ks * 32 + lq * 8);

  f32x4 acc[2];
#pragma unroll
  for (int j = 0; j < 2; ++j) acc[j] = (f32x4){0.f, 0.f, 0.f, 0.f};
#pragma unroll
  for (int j = 0; j < 2; ++j) {
    const unsigned short* wb = w1 + (size_t)((wave * 2 + j) * 16 + lr) * HID + lq * 8;
#pragma unroll
    for (int ks = 0; ks < 4; ++ks) {
      const bf16x8 b = *reinterpret_cast<const bf16x8*>(wb + ks * 32);
      acc[j] = __builtin_amdgcn_mfma_f32_16x16x32_bf16(a[ks], b, acc[j], 0, 0, 0);
    }
  }

#pragma unroll
  for (int j = 0; j < 2; ++j) {
    const int cc = (wave * 2 + j) * 16 + lr;
#pragma unroll
    for (int r = 0; r < 4; ++r)
      yt[lq * 4 + r][cc] = f2bf(fmaxf(acc[j][r] + bs1[j], 0.f));
  }
  __syncthreads();

  bf16x8 a2[4];
#pragma unroll
  for (int ks = 0; ks < 4; ++ks)
    a2[ks] = *reinterpret_cast<const bf16x8*>(&yt[lr][ks * 32 + lq * 8]);

#pragma unroll
  for (int j = 0; j < 2; ++j) acc[j] = (f32x4){0.f, 0.f, 0.f, 0.f};
#pragma unroll
  for (int j = 0; j < 2; ++j) {
    const unsigned short* wb = w2 + (size_t)((wave * 2 + j) * 16 + lr) * HID + lq * 8;
#pragma unroll
    for (int ks = 0; ks < 4; ++ks) {
      const bf16x8 b = *reinterpret_cast<const bf16x8*>(wb + ks * 32);
      acc[j] = __builtin_amdgcn_mfma_f32_16x16x32_bf16(a2[ks], b, acc[j], 0, 0, 0);
    }
  }

#pragma unroll
  for (int j = 0; j < 2; ++j)
#pragma unroll
    for (int r = 0; r < 4; ++r)
      acc[j][r] += bs2[j] + hres[j][r];

#pragma unroll
  for (int r = 0; r < 4; ++r) {
    float s = acc[0][r] + acc[1][r];
    float ss = acc[0][r] * acc[0][r] + acc[1][r] * acc[1][r];
#pragma unroll
    for (int m = 1; m < 16; m <<= 1) {
      s += __shfl_xor(s, m, 64);
      ss += __shfl_xor(ss, m, 64);
    }
    if (lr == 0) {
      lnp[lq * 4 + r][wave][0] = s;
      lnp[lq * 4 + r][wave][1] = ss;
    }
  }
  __syncthreads();

  float mu_[4], rstd_[4];
#pragma unroll
  for (int r = 0; r < 4; ++r) {
    const int rt = lq * 4 + r;
    float s = 0.f, ss = 0.f;
#pragma unroll
    for (int w = 0; w < 4; ++w) {
      const float2 p = *reinterpret_cast<const float2*>(&lnp[rt][w][0]);
      s += p.x;
      ss += p.y;
    }
    const float mu = s * (1.f / 128.f);
    const float var = ss * (1.f / 128.f) - mu * mu;
    mu_[r] = mu;
    rstd_[r] = rsqrtf(var + LN_EPS);
  }
#pragma unroll
  for (int j = 0; j < 2; ++j) {
    const int cc = (wave * 2 + j) * 16 + lr;
#pragma unroll
    for (int r = 0; r < 4; ++r) {
      const int row = row0 + lq * 4 + r;
      const float o = (acc[j][r] - mu_[r]) * rstd_[r] * gg[j] + bb[j];
      out[(size_t)row * HID + cc] = fmaxf(o, 0.f);
    }
  }
}

extern "C" void kernel_launch(void* const* d_in, const int* in_sizes, int n_in,
                              void* d_out, int out_size, void* d_ws, size_t ws_size,
                              hipStream_t stream) {
  const float* h     = (const float*)d_in[0];
  const int*   ei    = (const int*)d_in[1];
  const float* W1    = (const float*)d_in[2];
  const float* b1    = (const float*)d_in[3];
  const float* W2    = (const float*)d_in[4];
  const float* b2    = (const float*)d_in[5];
  const float* eps   = (const float*)d_in[6];
  const float* gamma = (const float*)d_in[7];
  const float* beta  = (const float*)d_in[8];

  const int nNodes = in_sizes[0] / HID;     // 50000
  const int nE     = in_sizes[1] / 2;       // 640000
  const int nb     = (nNodes + 255) / 256;  // 196
  const int nh4    = nNodes * HID / 4;      // 1.6M
  const int nw4    = HID * HID / 4;         // 4096

  // ws layout (ints; bf16 regions 16B-aligned):
  // counts[50000*CPAD=1.6M] | st[196 ull] | offsets[50001] | rank[640000] | esrc[640000] | hbf | zbf | w1bf | w2bf
  int* counts  = (int*)d_ws;                                  // 6.4 MB padded counters
  unsigned long long* st = (unsigned long long*)(counts + (size_t)nNodes * CPAD);
  int* offsets = (int*)(st + nb);                             // @int 1600392
  int* rank    = counts + 1650400;                            // byte 6,601,600 (16B-aligned)
  int* esrc    = rank + nE;
  unsigned short* hbf  = (unsigned short*)(esrc + nE);        // 16B-aligned
  unsigned short* zbf  = hbf + (size_t)nNodes * HID;          // +12.8 MB
  unsigned short* w1bf = zbf + (size_t)nNodes * HID;          // +12.8 MB
  unsigned short* w2bf = w1bf + HID * HID;                    // +32 KB (total ~37.6 MB)

  // zero padded counters + lookback state (one memset, ~6.4 MB ≈ 1 µs)
  hipMemsetAsync(counts, 0, (size_t)nNodes * CPAD * sizeof(int) + nb * sizeof(unsigned long long), stream);

  const int EB = (nE + 255) / 256;          // 2500 edge blocks
  k_cvt_rank<<<EB + 2048, 256, 0, stream>>>(h, W1, W2, (uint2*)hbf, (uint2*)w1bf, (uint2*)w2bf,
                                            nh4, nw4, ei, counts, rank, nE, EB);
  k_scanLB<<<nb, 256, 0, stream>>>(counts, offsets, st, nNodes, nb);
  k_scat<<<EB, 256, 0, stream>>>(ei, rank, offsets, esrc, nE);

  k_gather<<<(nNodes * 16 + 255) / 256, 256, 0, stream>>>(hbf, offsets, esrc, eps, zbf, nNodes);

  const int nTiles = nNodes / 16;            // 3125
  k_mmf<<<nTiles, 256, 0, stream>>>(zbf, w1bf, w2bf, b1, b2, hbf, gamma, beta,
                                    (float*)d_out);
}